// Round 3
// baseline (2271.642 us; speedup 1.0000x reference)
//
#include <hip/hip_runtime.h>

#define PI_F 3.14159265358979323846f

#define NCH   1000
#define NPTS  30000
#define NHALF 15000      // NPTS/2 packed complex samples
#define NFFT  32768      // complex FFT length (real length 65536)
#define NBF32 1024       // butterflies per channel per radix-32 pass (NFFT/32)
#define STR   32770      // per-channel stride in complex elements
#define XCOR  59999

__device__ __forceinline__ float2 cadd(float2 a, float2 b){ return make_float2(a.x+b.x, a.y+b.y); }
__device__ __forceinline__ float2 csub(float2 a, float2 b){ return make_float2(a.x-b.x, a.y-b.y); }
__device__ __forceinline__ float2 cmul(float2 a, float2 b){ return make_float2(a.x*b.x - a.y*b.y, a.x*b.y + a.y*b.x); }

template<int S>
__device__ __forceinline__ float2 mulIs(float2 z){ return make_float2(-(float)S*z.y, (float)S*z.x); }

// 8-point DFT, ω = e^{S*2πi/8}
template<int S>
__device__ __forceinline__ void dft8(float2 v[8]){
  const float r2 = 0.7071067811865476f;
  const float sf = (float)S;
  float2 ea=cadd(v[0],v[4]), eb=csub(v[0],v[4]);
  float2 ec=cadd(v[2],v[6]), ed=csub(v[2],v[6]);
  float2 oa=cadd(v[1],v[5]), ob=csub(v[1],v[5]);
  float2 oc=cadd(v[3],v[7]), od=csub(v[3],v[7]);
  float2 ied=mulIs<S>(ed), iod=mulIs<S>(od);
  float2 E0=cadd(ea,ec), E2=csub(ea,ec), E1=cadd(eb,ied), E3=csub(eb,ied);
  float2 O0=cadd(oa,oc), O2=csub(oa,oc), O1=cadd(ob,iod), O3=csub(ob,iod);
  float2 T1 = make_float2(r2*(O1.x - sf*O1.y), r2*(O1.y + sf*O1.x));
  float2 T2 = mulIs<S>(O2);
  float2 T3 = make_float2(r2*(-O3.x - sf*O3.y), r2*(sf*O3.x - O3.y));
  v[0]=cadd(E0,O0); v[4]=csub(E0,O0);
  v[1]=cadd(E1,T1); v[5]=csub(E1,T1);
  v[2]=cadd(E2,T2); v[6]=csub(E2,T2);
  v[3]=cadd(E3,T3); v[7]=csub(E3,T3);
}

template<int S>
__device__ __forceinline__ void dft4(float2 v[4]){
  float2 t0=cadd(v[0],v[2]), t1=csub(v[0],v[2]);
  float2 t2=cadd(v[1],v[3]), t3=mulIs<S>(csub(v[1],v[3]));
  v[0]=cadd(t0,t2); v[2]=csub(t0,t2);
  v[1]=cadd(t1,t3); v[3]=csub(t1,t3);
}

// 32-point DFT in registers
template<int S>
__device__ __forceinline__ void dft32(float2 v[32]){
  constexpr float TC[22] = {
    1.f, 0.98078528040323044f, 0.92387953251128674f, 0.83146961230254524f,
    0.70710678118654757f, 0.55557023301960218f, 0.38268343236508978f, 0.19509032201612825f,
    0.f, -0.19509032201612825f, -0.38268343236508978f, -0.55557023301960218f,
    -0.70710678118654757f, -0.83146961230254524f, -0.92387953251128674f, -0.98078528040323044f,
    -1.f, -0.98078528040323044f, -0.92387953251128674f, -0.83146961230254524f,
    -0.70710678118654757f, -0.55557023301960218f };
  constexpr float TS[22] = {
    0.f, 0.19509032201612825f, 0.38268343236508978f, 0.55557023301960218f,
    0.70710678118654757f, 0.83146961230254524f, 0.92387953251128674f, 0.98078528040323044f,
    1.f, 0.98078528040323044f, 0.92387953251128674f, 0.83146961230254524f,
    0.70710678118654757f, 0.55557023301960218f, 0.38268343236508978f, 0.19509032201612825f,
    0.f, -0.19509032201612825f, -0.38268343236508978f, -0.55557023301960218f,
    -0.70710678118654757f, -0.83146961230254524f };
  float2 y[4][8];
  #pragma unroll
  for (int b = 0; b < 4; ++b)
    #pragma unroll
    for (int a = 0; a < 8; ++a) y[b][a] = v[4*a + b];
  #pragma unroll
  for (int b = 0; b < 4; ++b) dft8<S>(y[b]);
  #pragma unroll
  for (int b = 1; b < 4; ++b)
    #pragma unroll
    for (int k1 = 1; k1 < 8; ++k1) {
      int m = b*k1;
      float2 w = make_float2(TC[m], (float)S * TS[m]);
      y[b][k1] = cmul(y[b][k1], w);
    }
  #pragma unroll
  for (int k1 = 0; k1 < 8; ++k1) {
    float2 z[4] = { y[0][k1], y[1][k1], y[2][k1], y[3][k1] };
    dft4<S>(z);
    #pragma unroll
    for (int k2 = 0; k2 < 4; ++k2) v[k1 + 8*k2] = z[k2];
  }
}

template<int S>
__device__ __forceinline__ void stage_twiddle32(float2 v[32], float ang){
  float s1,c1,s8,c8;
  __sincosf(ang, &s1, &c1);
  __sincosf(8.f*ang, &s8, &c8);
  float2 w1 = make_float2(c1, s1), w8 = make_float2(c8, s8);
  float2 w16 = cmul(w8, w8), w24 = cmul(w16, w8);
  float2 base[4] = { make_float2(1.f, 0.f), w8, w16, w24 };
  #pragma unroll
  for (int m = 0; m < 4; ++m) {
    float2 wr = base[m];
    if (m > 0) v[8*m] = cmul(v[8*m], wr);
    #pragma unroll
    for (int l = 1; l < 8; ++l) { wr = cmul(wr, w1); v[8*m+l] = cmul(v[8*m+l], wr); }
  }
}

// ---------- forward pass 1 (Ns=1, radix-32), fused with real-pair packing + zero pad ----------
__global__ __launch_bounds__(256) void fft_fwd_p1_r32(const float* __restrict__ d1, const float* __restrict__ d2,
                                                      float2* __restrict__ out, int cb, int ch0)
{
  int tid = blockIdx.x*256 + threadIdx.x;
  int c = tid >> 10;
  int j = tid & (NBF32-1);
  const float* src = (c < cb) ? (d1 + (size_t)(ch0 + c) * NPTS)
                              : (d2 + (size_t)(ch0 + c - cb) * NPTS);
  const float2* src2 = reinterpret_cast<const float2*>(src);
  float2 v[32];
  #pragma unroll
  for (int r = 0; r < 32; ++r) {
    int m = j + (r << 10);
    v[r] = (m < NHALF) ? src2[m] : make_float2(0.f, 0.f);
  }
  dft32<-1>(v);
  float2* dst = out + (size_t)c * STR + (size_t)j * 32;
  #pragma unroll
  for (int r = 0; r < 32; r += 2)
    *reinterpret_cast<float4*>(dst + r) = make_float4(v[r].x, v[r].y, v[r+1].x, v[r+1].y);
}

// ---------- generic Stockham radix-32 pass, Ns = 2^LG ----------
template<int LG, int S>
__global__ __launch_bounds__(256) void fft_pass32(const float2* __restrict__ in, float2* __restrict__ out)
{
  int tid = blockIdx.x*256 + threadIdx.x;
  int c = tid >> 10;
  int j = tid & (NBF32-1);
  const float2* src = in + (size_t)c * STR;
  float2 v[32];
  #pragma unroll
  for (int r = 0; r < 32; ++r) v[r] = src[j + (r << 10)];
  constexpr int NS = 1 << LG;
  int jm = j & (NS - 1);
  if constexpr (LG > 0) {
    float ang = (float)S * (2.0f*PI_F) * (float)jm / (float)(NS*32);
    stage_twiddle32<S>(v, ang);
  }
  dft32<S>(v);
  int idxD = ((j >> LG) << (LG+5)) + jm;
  float2* dst = out + (size_t)c * STR + idxD;
  #pragma unroll
  for (int r = 0; r < 32; ++r) dst[(size_t)(r << LG)] = v[r];
}

// ================= MEGA: final fwd stage + rfft-unpack + whiten + cross + irfft-pack =================
// Thread t holds (after final stage) Z[t + r*1024], r=0..31.
// Unpack pairs (k, 32768-k): k=i*1024+t needs Z[32768-k] = chunk 31-i, elem 1024-t -> LDS exchange.
// X[k] = xe + w*xo,  X[32768-k] = conj(xe - w*xo)  (shared products).
// Slot map after unpack: v[i] (i<16) = X[i*1024+t]; v[c] (c>=16) = X[c*1024 + e0], e0 = (t==0)?1024:1024-t.
// (thread 0: slots 16..31 hold bins (c+1)*1024, slot 31 = bin 32768; bin 16384 in a dedicated reg.)

__device__ __forceinline__ float smooth_at(int k, const float* s, float S32v, float a0, float alast){
  int hi = k + 327;
  float Shi = (hi >= 32768) ? S32v : s[hi];
  int lo = k - 328;
  float Slo = (lo >= 0) ? s[lo] : 0.f;
  float lc = (k < 327) ? (float)(327 - k) : 0.f;
  float rc = (k > 32441) ? (float)(k - 32441) : 0.f;
  return (lc*a0 + (Shi - Slo) + rc*alast) * (1.0f/655.0f);
}

__device__ __forceinline__ void whiten_one(const float2* __restrict__ src, int t, int lane, int wid,
                                           float* s, float* wt, float2* ex, float2* t0ext,
                                           float* p_mag32, float* p_S32,
                                           float2 v[32], float2& X16)
{
  // ---- load + final forward radix-32 stage (LG=10) ----
  #pragma unroll
  for (int r = 0; r < 32; ++r) v[r] = src[t + (r << 10)];
  stage_twiddle32<-1>(v, -(2.0f*PI_F) * (float)t * (1.0f/32768.0f));
  dft32<-1>(v);

  // ---- thread-0 snapshot of its own mirror sources (chunk 32-i elem 0) ----
  if (t == 0) {
    t0ext[0] = v[0];                       // chunk-32 wrap -> Z[0]
    #pragma unroll
    for (int i = 1; i < 16; ++i) t0ext[i] = v[32 - i];
    X16 = make_float2(v[16].x, -v[16].y);  // X[16384] = conj(Z[16384])
  }

  // unpack twiddle recurrence: w(k)=e^{-i pi k/32768}, step e^{-i pi/32}
  const float UC = 0.99518472667219693f, US = 0.09801714032956060f;
  float2 wstep = make_float2(UC, -US);
  float s0, c0; __sincosf(-PI_F*(float)t*(1.0f/32768.0f), &s0, &c0);
  float2 wcur = make_float2(c0, s0);

  __syncthreads();   // guard: previous use of s/ex finished
  // ---- round A: exchange chunks 24..31, unpack i=0..7 ----
  #pragma unroll
  for (int cc = 24; cc < 32; ++cc) ex[((cc-24)<<10) + t] = v[cc];
  __syncthreads();
  #pragma unroll
  for (int i = 0; i < 8; ++i) {
    int cm = 31 - i;
    float2 zn = (t == 0) ? t0ext[i] : ex[((cm-24)<<10) + (1024 - t)];
    float2 zk = v[i];
    float2 xe = make_float2(0.5f*(zk.x+zn.x), 0.5f*(zk.y-zn.y));
    float2 xh = make_float2(0.5f*(zk.x-zn.x), 0.5f*(zk.y+zn.y));
    float2 xo = make_float2(xh.y, -xh.x);
    float2 p  = cmul(wcur, xo);
    v[i]  = cadd(xe, p);
    v[cm] = make_float2(xe.x - p.x, -(xe.y - p.y));
    wcur = cmul(wcur, wstep);
  }
  __syncthreads();
  // ---- round B: exchange chunks 16..23, unpack i=8..15 ----
  #pragma unroll
  for (int cc = 16; cc < 24; ++cc) ex[((cc-16)<<10) + t] = v[cc];
  __syncthreads();
  #pragma unroll
  for (int i = 8; i < 16; ++i) {
    int cm = 31 - i;
    float2 zn = (t == 0) ? t0ext[i] : ex[((cm-16)<<10) + (1024 - t)];
    float2 zk = v[i];
    float2 xe = make_float2(0.5f*(zk.x+zn.x), 0.5f*(zk.y-zn.y));
    float2 xh = make_float2(0.5f*(zk.x-zn.x), 0.5f*(zk.y+zn.y));
    float2 xo = make_float2(xh.y, -xh.x);
    float2 p  = cmul(wcur, xo);
    v[i]  = cadd(xe, p);
    v[cm] = make_float2(xe.x - p.x, -(xe.y - p.y));
    wcur = cmul(wcur, wstep);
  }
  __syncthreads();

  // ---- magnitudes -> s[] ----
  #pragma unroll
  for (int i = 0; i < 16; ++i) s[(i<<10) + t] = sqrtf(v[i].x*v[i].x + v[i].y*v[i].y);
  if (t != 0) {
    #pragma unroll
    for (int cc = 16; cc < 32; ++cc) s[(cc<<10) + (1024 - t)] = sqrtf(v[cc].x*v[cc].x + v[cc].y*v[cc].y);
  } else {
    #pragma unroll
    for (int cc = 16; cc < 31; ++cc) s[((cc+1)<<10)] = sqrtf(v[cc].x*v[cc].x + v[cc].y*v[cc].y);
    *p_mag32 = sqrtf(v[31].x*v[31].x + v[31].y*v[31].y);
    s[16384] = sqrtf(X16.x*X16.x + X16.y*X16.y);
  }
  __syncthreads();

  // ---- block-wide inclusive scan (column layout, conflict-free) ----
  float col[32];
  #pragma unroll
  for (int cc = 0; cc < 32; ++cc) col[cc] = s[(cc<<10) + t];
  #pragma unroll
  for (int off = 1; off < 64; off <<= 1) {
    #pragma unroll
    for (int cc = 0; cc < 32; ++cc) {
      float u = __shfl_up(col[cc], off);
      if (lane >= off) col[cc] += u;
    }
  }
  if (lane == 63) {
    #pragma unroll
    for (int cc = 0; cc < 32; ++cc) wt[cc*16 + wid] = col[cc];
  }
  __syncthreads();
  if (wid == 0) {
    #pragma unroll
    for (int g = 0; g < 8; ++g) {
      int cc = g*4 + (lane >> 4), w = lane & 15;
      float vv = wt[cc*16 + w];
      #pragma unroll
      for (int off = 1; off < 16; off <<= 1) {
        float u = __shfl_up(vv, off);
        if ((lane & 15) >= off) vv += u;
      }
      wt[cc*16 + w] = vv;   // inclusive over waves
    }
  }
  __syncthreads();
  float Oacc = 0.f, lastS = 0.f;
  #pragma unroll
  for (int cc = 0; cc < 32; ++cc) {
    float wexcl = (wid > 0) ? wt[cc*16 + wid - 1] : 0.f;
    float Sv = Oacc + wexcl + col[cc];
    s[(cc<<10) + t] = Sv;
    lastS = Sv;
    Oacc += wt[cc*16 + 15];
  }
  if (t == 1023) *p_S32 = lastS + *p_mag32;
  __syncthreads();

  // ---- whiten + taper (W in place) ----
  float a0 = s[0];
  float alast = *p_mag32;
  float S32v = *p_S32;
  const float HS = PI_F / 39320.0f;
  float hss, hsc; __sincosf(1024.0f*HS, &hss, &hsc);
  float2 hstep = make_float2(hsc, hss);
  float us_, uc_;
  __sincosf(((float)t - 13108.0f) * HS, &us_, &uc_);
  float2 u = make_float2(uc_, us_);
  #pragma unroll
  for (int i = 0; i < 16; ++i) {
    int k = (i<<10) + t;
    float sm = smooth_at(k, s, S32v, a0, alast);
    float tp = 1.0f;
    if (k >= 13108) tp = u.x*u.x;
    else if (k < 131) { float sn2 = __sinf((float)k * (PI_F/260.0f)); tp = sn2*sn2; }
    float g = (sm > 0.f) ? tp / sm : 0.f;
    v[i] = make_float2(v[i].x*g, v[i].y*g);
    u = cmul(u, hstep);
  }
  int e0 = (t == 0) ? 1024 : (1024 - t);
  __sincosf(((float)(16384 + e0) - 13108.0f) * HS, &us_, &uc_);
  u = make_float2(uc_, us_);
  #pragma unroll
  for (int cc = 16; cc < 32; ++cc) {
    int k = (cc<<10) + e0;
    float sm = smooth_at(k, s, S32v, a0, alast);
    float tp = u.x*u.x;          // all these bins >= 16385 > 13108
    float g = (sm > 0.f) ? tp / sm : 0.f;
    v[cc] = make_float2(v[cc].x*g, v[cc].y*g);
    u = cmul(u, hstep);
  }
  if (t == 0) {
    float sm = smooth_at(16384, s, S32v, a0, alast);
    float ct = __cosf(3276.0f * HS);
    float tp = ct*ct;
    float g = (sm > 0.f) ? tp / sm : 0.f;
    X16 = make_float2(X16.x*g, X16.y*g);
  }
}

__global__ __launch_bounds__(1024) void mega_whiten_cross(const float2* __restrict__ in,
                                                          float2* __restrict__ zo, int cb)
{
  const int c = blockIdx.x;
  const int t = threadIdx.x;
  const int lane = t & 63, wid = t >> 6;

  __shared__ __align__(16) float s[32768];   // mags -> cumsum (also aliased as exchange buf)
  __shared__ float wt[512];
  __shared__ float2 t0ext[16];
  __shared__ float sc_mag32, sc_S32;
  float2* ex = reinterpret_cast<float2*>(s);

  const float2* src1 = in + (size_t)c * STR;
  const float2* src2 = in + (size_t)(cb + c) * STR;

  float2 W1[32]; float2 W16_1 = make_float2(0.f, 0.f);
  whiten_one(src1, t, lane, wid, s, wt, ex, t0ext, &sc_mag32, &sc_S32, W1, W16_1);
  float2 W2[32]; float2 W16_2 = make_float2(0.f, 0.f);
  whiten_one(src2, t, lane, wid, s, wt, ex, t0ext, &sc_mag32, &sc_S32, W2, W16_2);

  // ---- cross-spectrum C = conj(W1)*W2 and irfft pack, all in registers ----
  float ps_, pc_; __sincosf(PI_F*(float)t*(1.0f/32768.0f), &ps_, &pc_);
  float2 pw = make_float2(pc_, ps_);
  const float2 pstep = make_float2(0.99518472667219693f, 0.09801714032956060f); // e^{+i pi/32}
  const float scale = 1.0f/32768.0f;
  float2* dst = zo + (size_t)c * STR;
  #pragma unroll
  for (int i = 0; i < 16; ++i) {
    int k = (i<<10) + t;
    float2 A = W1[i],    B = W2[i];
    float2 Am = W1[31-i], Bm = W2[31-i];
    float2 Ck = make_float2(A.x*B.x + A.y*B.y,   A.x*B.y - A.y*B.x);
    float2 Cm = make_float2(Am.x*Bm.x + Am.y*Bm.y, Am.x*Bm.y - Am.y*Bm.x);
    float cs = pw.x, sn = pw.y;
    {
      float2 xe = make_float2(0.5f*(Ck.x+Cm.x), 0.5f*(Ck.y-Cm.y));
      float2 d  = make_float2(0.5f*(Ck.x-Cm.x), 0.5f*(Ck.y+Cm.y));
      float2 xo = cmul(make_float2(cs, sn), d);
      dst[k] = make_float2((xe.x - xo.y)*scale, (xe.y + xo.x)*scale);
    }
    if (!(t == 0 && i == 0)) {
      float2 xe = make_float2(0.5f*(Cm.x+Ck.x), 0.5f*(Cm.y-Ck.y));
      float2 d  = make_float2(0.5f*(Cm.x-Ck.x), 0.5f*(Cm.y+Ck.y));
      float2 xo = cmul(make_float2(-cs, sn), d);
      int km = 32768 - k;
      dst[km] = make_float2((xe.x - xo.y)*scale, (xe.y + xo.x)*scale);
    }
    pw = cmul(pw, pstep);
  }
  if (t == 0) {
    float2 A = W16_1, B = W16_2;
    float2 C16 = make_float2(A.x*B.x + A.y*B.y, A.x*B.y - A.y*B.x);
    dst[16384] = make_float2(C16.x*scale, -C16.y*scale);  // conj(C16)/N
  }
}

// ---------- inverse final pass (Ns=1024, radix-32), fused unpack + roll + slice ----------
__global__ __launch_bounds__(256) void fft_inv_final32(const float2* __restrict__ in, float* __restrict__ out, int ch0)
{
  int tid = blockIdx.x*256 + threadIdx.x;
  int c = tid >> 10;
  int j = tid & (NBF32-1);
  const float2* src = in + (size_t)c * STR;
  float2 v[32];
  #pragma unroll
  for (int r = 0; r < 32; ++r) v[r] = src[j + (r << 10)];
  float ang = (2.0f*PI_F) * (float)j * (1.0f/32768.0f);
  stage_twiddle32<1>(v, ang);
  dft32<1>(v);
  float* o = out + (size_t)(ch0 + c) * XCOR;
  #pragma unroll
  for (int r = 0; r < 32; ++r) {
    int n = j + (r << 10);
    int m = 2*n;
    int j1 = (m <= 29999) ? (m + 29999) : ((m >= 35537) ? (m - 35537) : -1);
    if (j1 >= 0) o[j1] = v[r].x;
    int m2 = m + 1;
    int j2 = (m2 <= 29999) ? (m2 + 29999) : ((m2 >= 35537) ? (m2 - 35537) : -1);
    if (j2 >= 0) o[j2] = v[r].y;
  }
}

__global__ void diag_kernel(float* out, float vv){ if (threadIdx.x==0 && blockIdx.x==0) out[0] = vv; }

extern "C" void kernel_launch(void* const* d_in, const int* in_sizes, int n_in,
                              void* d_out, int out_size, void* d_ws, size_t ws_size,
                              hipStream_t stream)
{
  const float* d1 = (const float*)d_in[0];
  const float* d2 = (const float*)d_in[1];
  float* out = (float*)d_out;

  const size_t bytesPerCh = 2ULL * 2ULL * (size_t)STR * sizeof(float2);
  int CB = (int)(ws_size / bytesPerCh);
  if (CB > NCH) CB = NCH;
  if (CB < 1) { diag_kernel<<<1,1,0,stream>>>(out, (float)ws_size); return; }

  float2* bufA = (float2*)d_ws;
  float2* bufB = bufA + (size_t)2 * CB * STR;

  for (int ch0 = 0; ch0 < NCH; ch0 += CB) {
    int cb = (NCH - ch0 < CB) ? (NCH - ch0) : CB;
    int nch2 = 2*cb;
    dim3 thr(256);

    // forward FFT stages 1,2 (both arrays batched)
    fft_fwd_p1_r32    <<<dim3(nch2*4), thr, 0, stream>>>(d1, d2, bufA, cb, ch0);
    fft_pass32<5,-1>  <<<dim3(nch2*4), thr, 0, stream>>>(bufA, bufB);

    // fused: final fwd stage + rfft unpack + whiten + cross + irfft pack
    mega_whiten_cross <<<dim3(cb), dim3(1024), 0, stream>>>(bufB, bufA, cb);

    // inverse FFT, 3 radix-32 passes; final fused with roll + central slice
    fft_pass32<0,1>   <<<dim3(cb*4), thr, 0, stream>>>(bufA, bufB);
    fft_pass32<5,1>   <<<dim3(cb*4), thr, 0, stream>>>(bufB, bufA);
    fft_inv_final32   <<<dim3(cb*4), thr, 0, stream>>>(bufA, out, ch0);
  }
}